// Round 3
// baseline (611.965 us; speedup 1.0000x reference)
//
#include <hip/hip_runtime.h>

// CrossAttention (B=8, Sq=Skv=2048, D=1024), fp32 in/out, bf16 MFMA compute.
//
// Workspace-lean pipeline (d_ws need: 107 MB; Q parked in d_out):
//   1) cvt fp32->bf16: x->xbf, ctx->cbf, Wq/Wk/Wv
//   2) Q = x@Wq^T * (1/32)  -> bf16, stored in d_out[0 : 33.5MB]
//      K = ctx@Wk^T         -> bf16, overlays dead xbf
//      Vt[b,e,t] = Wv@ctx^T -> bf16 (V transposed so PV is NT)
//   3) two passes over batch groups {4-7} then {0-3} (descending so out-f32
//      writes never clobber still-needed Q-bf16 in d_out):
//        S[b',s,t] = Q@K^T (bf16 out, overlays dead cbf)
//        softmax rows in-place (bf16 -> bf16)
//        out = P@Vt^T (f32 into d_out)
//
// GEMM = m97 structure: 128x128 tile, BK=32, 256 thr (4 waves, each 64x64 via
// 4x4 mfma_f32_16x16x32_bf16), global_load_lds width=16 staging, 2-barrier K-loop.

typedef unsigned short u16;
typedef __bf16 bf16x8 __attribute__((ext_vector_type(8)));
typedef float f32x4 __attribute__((ext_vector_type(4)));
typedef u16 us8 __attribute__((ext_vector_type(8)));

__device__ __forceinline__ u16 f2bf(float f) {
  unsigned int u = __float_as_uint(f);
  u += 0x7fffu + ((u >> 16) & 1u);   // round-to-nearest-even
  return (u16)(u >> 16);
}
__device__ __forceinline__ float bf2f(u16 h) {
  return __uint_as_float((unsigned int)h << 16);
}

struct __attribute__((aligned(8))) us4 { u16 x, y, z, w; };

__global__ __launch_bounds__(256) void cvt_bf16(const float4* __restrict__ s,
                                                us4* __restrict__ d, int n4) {
  int i = blockIdx.x * 256 + threadIdx.x;
  if (i >= n4) return;
  float4 v = s[i];
  us4 o{f2bf(v.x), f2bf(v.y), f2bf(v.z), f2bf(v.w)};
  d[i] = o;
}

// C-style casts: static_cast cannot both drop const and change address space.
__device__ __forceinline__ void gload16(const u16* g, u16* l) {
  __builtin_amdgcn_global_load_lds(
      (const __attribute__((address_space(1))) unsigned int*)g,
      (__attribute__((address_space(3))) unsigned int*)l,
      16, 0, 0);
}

// NT GEMM: C[m,n] = scale * sum_k A[m,k]*B[n,k].  A:[M][lda] B:[N][ldb] bf16
// row-major, contraction along rows. grid = (N/128, M/128, batches).
template <bool BF16OUT>
__global__ __launch_bounds__(256) void gemm_nt(
    const u16* __restrict__ A, const u16* __restrict__ B, void* __restrict__ Cout,
    int lda, int ldb, int ldc, int K,
    long batchA, long batchB, long batchC, float scale) {
  __shared__ u16 sA[128 * 32];
  __shared__ u16 sB[128 * 32];

  const int tid  = threadIdx.x;
  const int lane = tid & 63;
  const int wv   = tid >> 6;          // wave 0..3
  const int z    = blockIdx.z;

  const u16* Ab = A + (size_t)z * batchA + (size_t)blockIdx.y * 128 * lda;
  const u16* Bb = B + (size_t)z * batchB + (size_t)blockIdx.x * 128 * ldb;

  // staging: wave wv loads rows [wv*32, wv*32+32) of each tile, two 16-row issues
  const int r0   = wv * 32;
  const int srow = lane >> 2;         // 0..15
  const int scol = (lane & 3) * 8;    // element col group (8 bf16 = 16B)

  const u16* gA0 = Ab + (size_t)(r0 + srow) * lda + scol;
  const u16* gA1 = Ab + (size_t)(r0 + 16 + srow) * lda + scol;
  const u16* gB0 = Bb + (size_t)(r0 + srow) * ldb + scol;
  const u16* gB1 = Bb + (size_t)(r0 + 16 + srow) * ldb + scol;

  // fragment addressing
  const int fr = lane & 15;           // m (A) / n (B) within 16
  const int fq = (lane >> 4) * 8;     // k offset within 32
  const int wm = (wv & 1) * 64;
  const int wn = (wv >> 1) * 64;

  f32x4 acc[4][4];
#pragma unroll
  for (int i = 0; i < 4; i++)
#pragma unroll
    for (int j = 0; j < 4; j++) acc[i][j] = (f32x4)0.f;

  for (int k0 = 0; k0 < K; k0 += 32) {
    gload16(gA0 + k0, &sA[r0 * 32]);
    gload16(gA1 + k0, &sA[(r0 + 16) * 32]);
    gload16(gB0 + k0, &sB[r0 * 32]);
    gload16(gB1 + k0, &sB[(r0 + 16) * 32]);
    __syncthreads();   // compiler drains vmcnt(0) before s_barrier

    bf16x8 av[4], bv[4];
#pragma unroll
    for (int i = 0; i < 4; i++)
      av[i] = *(const bf16x8*)&sA[(wm + i * 16 + fr) * 32 + fq];
#pragma unroll
    for (int i = 0; i < 4; i++)
      bv[i] = *(const bf16x8*)&sB[(wn + i * 16 + fr) * 32 + fq];
#pragma unroll
    for (int mi = 0; mi < 4; mi++)
#pragma unroll
      for (int ni = 0; ni < 4; ni++)
        acc[mi][ni] = __builtin_amdgcn_mfma_f32_16x16x32_bf16(
            av[mi], bv[ni], acc[mi][ni], 0, 0, 0);
    __syncthreads();   // protect LDS before next stage overwrites
  }

  // epilogue: C/D layout col=lane&15, row=(lane>>4)*4+reg  [m89/m91 verified]
  const size_t cbase = (size_t)z * batchC;
  const int row0 = blockIdx.y * 128 + wm + (lane >> 4) * 4;
  const int col0 = blockIdx.x * 128 + wn + fr;
#pragma unroll
  for (int mi = 0; mi < 4; mi++) {
#pragma unroll
    for (int i = 0; i < 4; i++) {
      const size_t roff = cbase + (size_t)(row0 + mi * 16 + i) * ldc + col0;
#pragma unroll
      for (int ni = 0; ni < 4; ni++) {
        float v = acc[mi][ni][i] * scale;
        if constexpr (BF16OUT)
          ((u16*)Cout)[roff + ni * 16] = f2bf(v);
        else
          ((float*)Cout)[roff + ni * 16] = v;
      }
    }
  }
}

// One block per row of 2048 bf16 logits -> bf16 probabilities, IN PLACE.
// Each block owns exactly its row: read fully, reduce, write back same bytes.
__global__ __launch_bounds__(256) void softmax_rows_bf16(u16* __restrict__ SP) {
  const size_t row = blockIdx.x;
  us8* p = (us8*)(SP + row * 2048);
  const int t = threadIdx.x;
  us8 raw = p[t];
  float v[8];
#pragma unroll
  for (int i = 0; i < 8; i++) v[i] = bf2f(raw[i]);

  float m = v[0];
#pragma unroll
  for (int i = 1; i < 8; i++) m = fmaxf(m, v[i]);
#pragma unroll
  for (int o = 32; o; o >>= 1) m = fmaxf(m, __shfl_xor(m, o, 64));
  __shared__ float redm[4];
  if ((t & 63) == 0) redm[t >> 6] = m;
  __syncthreads();
  m = fmaxf(fmaxf(redm[0], redm[1]), fmaxf(redm[2], redm[3]));

  float sum = 0.f;
#pragma unroll
  for (int i = 0; i < 8; i++) { v[i] = __expf(v[i] - m); sum += v[i]; }
#pragma unroll
  for (int o = 32; o; o >>= 1) sum += __shfl_xor(sum, o, 64);
  __shared__ float reds[4];
  if ((t & 63) == 0) reds[t >> 6] = sum;
  __syncthreads();
  sum = reds[0] + reds[1] + reds[2] + reds[3];
  const float r = 1.0f / sum;

  us8 o;
#pragma unroll
  for (int i = 0; i < 8; i++) o[i] = f2bf(v[i] * r);
  p[t] = o;
}

extern "C" void kernel_launch(void* const* d_in, const int* in_sizes, int n_in,
                              void* d_out, int out_size, void* d_ws, size_t ws_size,
                              hipStream_t stream) {
  const float* x   = (const float*)d_in[0];  // [8,2048,1024]
  const float* ctx = (const float*)d_in[1];  // [8,2048,1024]
  const float* Wq  = (const float*)d_in[2];  // [1024,1024]
  const float* Wk  = (const float*)d_in[3];
  const float* Wv  = (const float*)d_in[4];
  float* out = (float*)d_out;                // [8,2048,1024] f32

  const size_t NT = 8ull * 2048 * 1024;      // 16,777,216 elements

  // d_ws layout (total 107 MB):
  //   [0      , 33.5M) xbf  -> dead after Q  -> reused as Kbf
  //   [33.5M  , 67.1M) cbf  -> dead after Vt -> reused as S/P (4 batches bf16)
  //   [67.1M  , 100.6M) Vt  [b][e=1024][t=2048] bf16
  //   [100.6M , 106.9M) Wqb/Wkb/Wvb bf16
  char* ws = (char*)d_ws;
  u16* xbf  = (u16*)(ws);
  u16* Kbf  = (u16*)(ws);                    // overlays xbf (dead after Q)
  u16* cbf  = (u16*)(ws + NT * 2);
  u16* Sbuf = (u16*)(ws + NT * 2);           // overlays cbf (dead after Vt)
  u16* Vt   = (u16*)(ws + NT * 4);
  u16* Wqb  = (u16*)(ws + NT * 6);
  u16* Wkb  = (u16*)(ws + NT * 6 + 2097152);
  u16* Wvb  = (u16*)(ws + NT * 6 + 4194304);

  u16* Qbf = (u16*)d_out;                    // bf16 Q parked in output buffer

  dim3 blk(256);

  // 1) fp32 -> bf16
  cvt_bf16<<<dim3(16384), blk, 0, stream>>>((const float4*)x,   (us4*)xbf, 4194304);
  cvt_bf16<<<dim3(16384), blk, 0, stream>>>((const float4*)ctx, (us4*)cbf, 4194304);
  cvt_bf16<<<dim3(1024),  blk, 0, stream>>>((const float4*)Wq,  (us4*)Wqb, 262144);
  cvt_bf16<<<dim3(1024),  blk, 0, stream>>>((const float4*)Wk,  (us4*)Wkb, 262144);
  cvt_bf16<<<dim3(1024),  blk, 0, stream>>>((const float4*)Wv,  (us4*)Wvb, 262144);

  // 2) projections
  // Q = x @ Wq^T * 1/32 : M=16384 N=1024 K=1024  (into d_out)
  gemm_nt<true><<<dim3(8, 128, 1), blk, 0, stream>>>(
      xbf, Wqb, Qbf, 1024, 1024, 1024, 1024, 0, 0, 0, 0.03125f);
  // K = ctx @ Wk^T  (overlays dead xbf)
  gemm_nt<true><<<dim3(8, 128, 1), blk, 0, stream>>>(
      cbf, Wkb, Kbf, 1024, 1024, 1024, 1024, 0, 0, 0, 1.0f);
  // Vt[b,e,t] = Wv @ ctx_b^T : per batch M=1024 N=2048 K=1024
  gemm_nt<true><<<dim3(16, 8, 8), blk, 0, stream>>>(
      Wvb, cbf, Vt, 1024, 1024, 2048, 1024,
      0L, 2048L * 1024, 1024L * 2048, 1.0f);

  // 3) attention in two groups of 4 batches, DESCENDING so f32 out-writes in
  //    d_out never clobber Q-bf16 still needed by the later (lower) group.
  for (int p = 1; p >= 0; --p) {
    const long boff = (long)p * 4 * 2048 * 1024;      // token-major elem offset
    // S[b',s,t] = Q_b @ K_b^T : per batch M=2048 N=2048 K=1024, bf16 out
    gemm_nt<true><<<dim3(16, 16, 4), blk, 0, stream>>>(
        Qbf + boff, Kbf + boff, Sbuf, 1024, 1024, 2048, 1024,
        2048L * 1024, 2048L * 1024, 2048L * 2048, 1.0f);
    // softmax in place: 4*2048 = 8192 rows of 2048
    softmax_rows_bf16<<<dim3(8192), blk, 0, stream>>>(Sbuf);
    // out[b,s,e] = P_b @ Vt_b^T : per batch M=2048 N=1024 K=2048, f32 out
    gemm_nt<false><<<dim3(8, 16, 4), blk, 0, stream>>>(
        Sbuf, Vt + (long)p * 4 * 1024 * 2048, out + boff,
        2048, 2048, 1024, 2048,
        2048L * 2048, 1024L * 2048, 2048L * 1024, 1.0f);
  }
}

// Round 4
// 568.972 us; speedup vs baseline: 1.0756x; 1.0756x over previous
//
#include <hip/hip_runtime.h>

// CrossAttention (B=8, Sq=Skv=2048, D=1024), fp32 in/out, bf16 MFMA compute.
//
// Full-batch pipeline (ws usage 107 MB; Q AND K parked in d_out as bf16):
//   1) cvt fp32->bf16: {x,ctx} -> xbf,cbf ; {Wq*(1/32),Wk,Wv} -> Wqb,Wkb,Wvb
//   2) [Q|K] = [x|ctx] @ [Wq|Wk]^T  (one batched NT GEMM, z=0/1) -> d_out bf16
//      Vt[b,e,t] = Wv@ctx^T (V transposed so PV is NT)           -> ws
//   3) S[b,s,t] = Q@K^T (8 batches, 2048 blocks) -> bf16 S overlays dead xbf+cbf
//   4) softmax rows in place (16384 rows)
//   5) out = P@Vt^T (f32) -> d_out, overwriting dead Q/K (stream-ordered)
//
// GEMM = m97 structure: 128x128 tile, BK=32, 256 thr (4 waves, each 64x64 via
// 4x4 mfma_f32_16x16x32_bf16), global_load_lds width=16 staging, 2-barrier
// K-loop, XOR-swizzled LDS colgroups (kills 4-way bank conflicts).

typedef unsigned short u16;
typedef __bf16 bf16x8 __attribute__((ext_vector_type(8)));
typedef float f32x4 __attribute__((ext_vector_type(4)));
typedef u16 us8 __attribute__((ext_vector_type(8)));

__device__ __forceinline__ u16 f2bf(float f) {
  unsigned int u = __float_as_uint(f);
  u += 0x7fffu + ((u >> 16) & 1u);   // round-to-nearest-even
  return (u16)(u >> 16);
}
__device__ __forceinline__ float bf2f(u16 h) {
  return __uint_as_float((unsigned int)h << 16);
}

struct __attribute__((aligned(8))) us4 { u16 x, y, z, w; };

// x (4194304 float4) -> xbf ; ctx -> cbf. One dispatch.
__global__ __launch_bounds__(256) void cvt_xc(const float4* __restrict__ x,
                                              const float4* __restrict__ c,
                                              us4* __restrict__ dx,
                                              us4* __restrict__ dc) {
  int i = blockIdx.x * 256 + threadIdx.x;
  const float4* s = (i < 4194304) ? x : (c - 4194304);
  us4* d = (i < 4194304) ? dx : (dc - 4194304);
  float4 v = s[i];
  us4 o{f2bf(v.x), f2bf(v.y), f2bf(v.z), f2bf(v.w)};
  d[i] = o;
}

// Wq*(1/32), Wk, Wv -> bf16 (each 262144 float4). One dispatch, 3072 blocks.
__global__ __launch_bounds__(256) void cvt_w(const float4* __restrict__ wq,
                                             const float4* __restrict__ wk,
                                             const float4* __restrict__ wv,
                                             us4* __restrict__ d) {
  int i = blockIdx.x * 256 + threadIdx.x;
  const float4* s; float sc;
  if (i < 262144)      { s = wq;           sc = 0.03125f; }
  else if (i < 524288) { s = wk - 262144;  sc = 1.0f; }
  else                 { s = wv - 524288;  sc = 1.0f; }
  float4 v = s[i];
  us4 o{f2bf(v.x * sc), f2bf(v.y * sc), f2bf(v.z * sc), f2bf(v.w * sc)};
  d[i] = o;
}

// C-style casts: static_cast cannot both drop const and change address space.
__device__ __forceinline__ void gload16(const u16* g, u16* l) {
  __builtin_amdgcn_global_load_lds(
      (const __attribute__((address_space(1))) unsigned int*)g,
      (__attribute__((address_space(3))) unsigned int*)l,
      16, 0, 0);
}

// NT GEMM: C[m,n] = sum_k A[m,k]*B[n,k].  A:[M][lda] B:[N][ldb] bf16
// row-major, contraction along rows. grid = (N/128, M/128, batches).
// LDS layout: row r, colgroup slot s (8 elems) holds global colgroup s^(r&3).
template <bool BF16OUT>
__global__ __launch_bounds__(256) void gemm_nt(
    const u16* __restrict__ A, const u16* __restrict__ B, void* __restrict__ Cout,
    int lda, int ldb, int ldc, int K,
    long batchA, long batchB, long batchC) {
  __shared__ u16 sA[128 * 32];
  __shared__ u16 sB[128 * 32];

  const int tid  = threadIdx.x;
  const int lane = tid & 63;
  const int wv   = tid >> 6;          // wave 0..3
  const int z    = blockIdx.z;

  const u16* Ab = A + (size_t)z * batchA + (size_t)blockIdx.y * 128 * lda;
  const u16* Bb = B + (size_t)z * batchB + (size_t)blockIdx.x * 128 * ldb;

  // staging: wave wv loads rows [wv*32, wv*32+32), two 16-row issues per tile.
  // XOR swizzle: lane (srow, c) fetches global colgroup c^(srow&3).
  const int r0   = wv * 32;
  const int srow = lane >> 2;                        // 0..15
  const int scol = (((lane & 3) ^ (srow & 3))) * 8;  // swizzled source colgroup

  const u16* gA0 = Ab + (size_t)(r0 + srow) * lda + scol;
  const u16* gA1 = Ab + (size_t)(r0 + 16 + srow) * lda + scol;
  const u16* gB0 = Bb + (size_t)(r0 + srow) * ldb + scol;
  const u16* gB1 = Bb + (size_t)(r0 + 16 + srow) * ldb + scol;

  // fragment addressing: global k-group g = lane>>4 lives at slot g^(row&3)
  const int fr = lane & 15;           // m (A) / n (B) within 16
  const int g  = lane >> 4;           // k-group 0..3
  const int wm = (wv & 1) * 64;
  const int wn = (wv >> 1) * 64;
  const int slot = (g ^ (fr & 3)) * 8;   // row&3 == fr&3 for all row = base+fr

  f32x4 acc[4][4];
#pragma unroll
  for (int i = 0; i < 4; i++)
#pragma unroll
    for (int j = 0; j < 4; j++) acc[i][j] = (f32x4)0.f;

  for (int k0 = 0; k0 < K; k0 += 32) {
    gload16(gA0 + k0, &sA[r0 * 32]);
    gload16(gA1 + k0, &sA[(r0 + 16) * 32]);
    gload16(gB0 + k0, &sB[r0 * 32]);
    gload16(gB1 + k0, &sB[(r0 + 16) * 32]);
    __syncthreads();   // compiler drains vmcnt(0) before s_barrier

    bf16x8 av[4], bv[4];
#pragma unroll
    for (int i = 0; i < 4; i++)
      av[i] = *(const bf16x8*)&sA[(wm + i * 16 + fr) * 32 + slot];
#pragma unroll
    for (int i = 0; i < 4; i++)
      bv[i] = *(const bf16x8*)&sB[(wn + i * 16 + fr) * 32 + slot];
#pragma unroll
    for (int mi = 0; mi < 4; mi++)
#pragma unroll
      for (int ni = 0; ni < 4; ni++)
        acc[mi][ni] = __builtin_amdgcn_mfma_f32_16x16x32_bf16(
            av[mi], bv[ni], acc[mi][ni], 0, 0, 0);
    __syncthreads();   // protect LDS before next stage overwrites
  }

  // epilogue: C/D layout col=lane&15, row=(lane>>4)*4+reg  [m89/m91 verified]
  const size_t cbase = (size_t)z * batchC;
  const int row0 = blockIdx.y * 128 + wm + (lane >> 4) * 4;
  const int col0 = blockIdx.x * 128 + wn + fr;
#pragma unroll
  for (int mi = 0; mi < 4; mi++) {
#pragma unroll
    for (int i = 0; i < 4; i++) {
      const size_t roff = cbase + (size_t)(row0 + mi * 16 + i) * ldc + col0;
#pragma unroll
      for (int ni = 0; ni < 4; ni++) {
        float v = acc[mi][ni][i];
        if constexpr (BF16OUT)
          ((u16*)Cout)[roff + ni * 16] = f2bf(v);
        else
          ((float*)Cout)[roff + ni * 16] = v;
      }
    }
  }
}

// One block per row of 2048 bf16 logits -> bf16 probabilities, IN PLACE.
__global__ __launch_bounds__(256) void softmax_rows_bf16(u16* __restrict__ SP) {
  const size_t row = blockIdx.x;
  us8* p = (us8*)(SP + row * 2048);
  const int t = threadIdx.x;
  us8 raw = p[t];
  float v[8];
#pragma unroll
  for (int i = 0; i < 8; i++) v[i] = bf2f(raw[i]);

  float m = v[0];
#pragma unroll
  for (int i = 1; i < 8; i++) m = fmaxf(m, v[i]);
#pragma unroll
  for (int o = 32; o; o >>= 1) m = fmaxf(m, __shfl_xor(m, o, 64));
  __shared__ float redm[4];
  if ((t & 63) == 0) redm[t >> 6] = m;
  __syncthreads();
  m = fmaxf(fmaxf(redm[0], redm[1]), fmaxf(redm[2], redm[3]));

  float sum = 0.f;
#pragma unroll
  for (int i = 0; i < 8; i++) { v[i] = __expf(v[i] - m); sum += v[i]; }
#pragma unroll
  for (int o = 32; o; o >>= 1) sum += __shfl_xor(sum, o, 64);
  __shared__ float reds[4];
  if ((t & 63) == 0) reds[t >> 6] = sum;
  __syncthreads();
  sum = reds[0] + reds[1] + reds[2] + reds[3];
  const float r = 1.0f / sum;

  us8 o;
#pragma unroll
  for (int i = 0; i < 8; i++) o[i] = f2bf(v[i] * r);
  p[t] = o;
}

extern "C" void kernel_launch(void* const* d_in, const int* in_sizes, int n_in,
                              void* d_out, int out_size, void* d_ws, size_t ws_size,
                              hipStream_t stream) {
  const float* x   = (const float*)d_in[0];  // [8,2048,1024]
  const float* ctx = (const float*)d_in[1];  // [8,2048,1024]
  const float* Wq  = (const float*)d_in[2];  // [1024,1024]
  const float* Wk  = (const float*)d_in[3];
  const float* Wv  = (const float*)d_in[4];
  float* out = (float*)d_out;                // [8,2048,1024] f32

  const size_t NT = 8ull * 2048 * 1024;      // 16,777,216 elements

  // d_ws layout (u16 elements; total 107 MB — same footprint as passing run):
  //   xbf [0,NT)  cbf [NT,2NT)  -> both dead after projections -> S overlays
  //   Vt  [2NT,3NT)   Wqb/Wkb/Wvb [3NT, 3NT+3M)
  u16* wsu  = (u16*)d_ws;
  u16* xbf  = wsu;
  u16* cbf  = wsu + NT;
  u16* Sbuf = wsu;                 // overlays xbf+cbf (67 MB, 8 batches)
  u16* Vt   = wsu + 2 * NT;
  u16* Wqb  = wsu + 3 * NT;        // Wqb,Wkb,Wvb contiguous (1M elems each)
  // d_out doubles as bf16 Q [0,NT) and K [NT,2NT) until PV overwrites it.
  u16* Qbf = (u16*)d_out;

  dim3 blk(256);

  // 1) converts (2 dispatches)
  cvt_xc<<<dim3(32768), blk, 0, stream>>>((const float4*)x, (const float4*)ctx,
                                          (us4*)xbf, (us4*)cbf);
  cvt_w<<<dim3(3072), blk, 0, stream>>>((const float4*)Wq, (const float4*)Wk,
                                        (const float4*)Wv, (us4*)Wqb);

  // 2) [Q|K] projection, batched z=0/1: A stride NT (xbf->cbf), B stride 1M
  //    (Wqb->Wkb), C stride NT (Q->K inside d_out). M=16384 N=1024 K=1024.
  gemm_nt<true><<<dim3(8, 128, 2), blk, 0, stream>>>(
      xbf, Wqb, Qbf, 1024, 1024, 1024, 1024,
      (long)NT, 1024L * 1024, (long)NT);
  // Vt[b,e,t] = Wv @ ctx_b^T : per batch M=1024 N=2048 K=1024
  gemm_nt<true><<<dim3(16, 8, 8), blk, 0, stream>>>(
      Wqb + 2 * 1024 * 1024, cbf, Vt, 1024, 1024, 2048, 1024,
      0L, 2048L * 1024, 1024L * 2048);

  // 3) S[b,s,t] = Q_b @ K_b^T : 8 batches, M=2048 N=2048 K=1024, bf16 out
  gemm_nt<true><<<dim3(16, 16, 8), blk, 0, stream>>>(
      Qbf, Qbf + NT, Sbuf, 1024, 1024, 2048, 1024,
      2048L * 1024, 2048L * 1024, 2048L * 2048);

  // 4) softmax in place: 16384 rows of 2048
  softmax_rows_bf16<<<dim3(16384), blk, 0, stream>>>(Sbuf);

  // 5) out[b,s,e] = P_b @ Vt_b^T : M=2048 N=1024 K=2048, f32 out (overwrites
  //    dead Q/K in d_out; stream-ordered after step 3/4)
  gemm_nt<false><<<dim3(8, 16, 8), blk, 0, stream>>>(
      Sbuf, Vt, out, 2048, 2048, 1024, 2048,
      2048L * 2048, 1024L * 2048, 2048L * 1024);
}

// Round 5
// 514.046 us; speedup vs baseline: 1.1905x; 1.1068x over previous
//
#include <hip/hip_runtime.h>

// CrossAttention (B=8, Sq=Skv=2048, D=1024), fp32 in/out, bf16 MFMA compute.
//
// Full-batch pipeline (ws usage 107 MB; Q AND K parked in d_out as bf16):
//   1) cvt fp32->bf16: {x,ctx} -> xbf,cbf ; {Wq*(1/32),Wk,Wv} -> Wqb,Wkb,Wvb
//   2) [Q|K] = [x|ctx] @ [Wq|Wk]^T  (one batched NT GEMM, z=0/1) -> d_out bf16
//      Vt[b,e,t] = Wv@ctx^T (V transposed so PV is NT)           -> ws
//   3) S[b,s,t] = Q@K^T (8 batches) -> bf16 S overlays dead xbf+cbf
//   4) softmax rows in place (16384 rows)
//   5) out = P@Vt^T (f32) -> d_out, overwriting dead Q/K (stream-ordered)
//
// GEMM: 256x128 block tile, BK=32, 512 thr = 8 waves, each wave the proven
// 64x64 4x4-fragment mfma_f32_16x16x32_bf16 engine; global_load_lds width=16
// staging; 2-barrier K-loop. 24 KB LDS -> 4 blocks/CU, 32 waves/CU.

typedef unsigned short u16;
typedef __bf16 bf16x8 __attribute__((ext_vector_type(8)));
typedef float f32x4 __attribute__((ext_vector_type(4)));
typedef u16 us8 __attribute__((ext_vector_type(8)));

__device__ __forceinline__ u16 f2bf(float f) {
  unsigned int u = __float_as_uint(f);
  u += 0x7fffu + ((u >> 16) & 1u);   // round-to-nearest-even
  return (u16)(u >> 16);
}
__device__ __forceinline__ float bf2f(u16 h) {
  return __uint_as_float((unsigned int)h << 16);
}

struct __attribute__((aligned(8))) us4 { u16 x, y, z, w; };

// x (4194304 float4) -> xbf ; ctx -> cbf. One dispatch.
__global__ __launch_bounds__(256) void cvt_xc(const float4* __restrict__ x,
                                              const float4* __restrict__ c,
                                              us4* __restrict__ dx,
                                              us4* __restrict__ dc) {
  int i = blockIdx.x * 256 + threadIdx.x;
  const float4* s = (i < 4194304) ? x : (c - 4194304);
  us4* d = (i < 4194304) ? dx : (dc - 4194304);
  float4 v = s[i];
  us4 o{f2bf(v.x), f2bf(v.y), f2bf(v.z), f2bf(v.w)};
  d[i] = o;
}

// Wq*(1/32), Wk, Wv -> bf16 (each 262144 float4). One dispatch, 3072 blocks.
__global__ __launch_bounds__(256) void cvt_w(const float4* __restrict__ wq,
                                             const float4* __restrict__ wk,
                                             const float4* __restrict__ wv,
                                             us4* __restrict__ d) {
  int i = blockIdx.x * 256 + threadIdx.x;
  const float4* s; float sc;
  if (i < 262144)      { s = wq;           sc = 0.03125f; }
  else if (i < 524288) { s = wk - 262144;  sc = 1.0f; }
  else                 { s = wv - 524288;  sc = 1.0f; }
  float4 v = s[i];
  us4 o{f2bf(v.x * sc), f2bf(v.y * sc), f2bf(v.z * sc), f2bf(v.w * sc)};
  d[i] = o;
}

// C-style casts: static_cast cannot both drop const and change address space.
__device__ __forceinline__ void gload16(const u16* g, u16* l) {
  __builtin_amdgcn_global_load_lds(
      (const __attribute__((address_space(1))) unsigned int*)g,
      (__attribute__((address_space(3))) unsigned int*)l,
      16, 0, 0);
}

// NT GEMM: C[m,n] = sum_k A[m,k]*B[n,k].  A:[M][lda] B:[N][ldb] bf16
// row-major, contraction along rows. grid = (N/128, M/256, batches), 512 thr.
template <bool BF16OUT>
__global__ __launch_bounds__(512) void gemm_nt(
    const u16* __restrict__ A, const u16* __restrict__ B, void* __restrict__ Cout,
    int lda, int ldb, int ldc, int K,
    long batchA, long batchB, long batchC) {
  __shared__ u16 sA[256 * 32];   // 16 KB
  __shared__ u16 sB[128 * 32];   //  8 KB

  const int tid  = threadIdx.x;          // 0..511
  const int lane = tid & 63;
  const int wv   = tid >> 6;             // wave 0..7
  const int z    = blockIdx.z;

  const u16* Ab = A + (size_t)z * batchA + (size_t)blockIdx.y * 256 * lda;
  const u16* Bb = B + (size_t)z * batchB + (size_t)blockIdx.x * 128 * ldb;

  // staging: 512 threads, 4 lanes per row (64-B contiguous runs).
  const int srow = tid >> 2;             // 0..127
  const int scol = (tid & 3) * 8;        // colgroup (8 bf16 = 16 B)

  const u16* gA0 = Ab + (size_t)srow * lda + scol;          // rows 0..127
  const u16* gA1 = Ab + (size_t)(128 + srow) * lda + scol;  // rows 128..255
  const u16* gB  = Bb + (size_t)srow * ldb + scol;          // rows 0..127

  // fragment addressing (per wave: 64x64 tile, 4x4 frags of 16x16x32)
  const int fr = lane & 15;              // m (A) / n (B) within 16
  const int fq = (lane >> 4) * 8;        // k offset within 32
  const int wm = (wv & 3) * 64;          // wave m-offset (0..192)
  const int wn = (wv >> 2) * 64;         // wave n-offset (0 or 64)

  f32x4 acc[4][4];
#pragma unroll
  for (int i = 0; i < 4; i++)
#pragma unroll
    for (int j = 0; j < 4; j++) acc[i][j] = (f32x4)0.f;

  for (int k0 = 0; k0 < K; k0 += 32) {
    // LDS dest = wave-uniform base + lane*16 (tid*16 decomposes as such)
    gload16(gA0 + k0, &sA[tid * 8]);
    gload16(gA1 + k0, &sA[4096 + tid * 8]);
    gload16(gB  + k0, &sB[tid * 8]);
    __syncthreads();   // compiler drains vmcnt(0) before s_barrier

    bf16x8 av[4], bv[4];
#pragma unroll
    for (int i = 0; i < 4; i++)
      av[i] = *(const bf16x8*)&sA[(wm + i * 16 + fr) * 32 + fq];
#pragma unroll
    for (int i = 0; i < 4; i++)
      bv[i] = *(const bf16x8*)&sB[(wn + i * 16 + fr) * 32 + fq];
#pragma unroll
    for (int mi = 0; mi < 4; mi++)
#pragma unroll
      for (int ni = 0; ni < 4; ni++)
        acc[mi][ni] = __builtin_amdgcn_mfma_f32_16x16x32_bf16(
            av[mi], bv[ni], acc[mi][ni], 0, 0, 0);
    __syncthreads();   // protect LDS before next stage overwrites
  }

  // epilogue: C/D layout col=lane&15, row=(lane>>4)*4+reg  [m89/m91 verified]
  const size_t cbase = (size_t)z * batchC;
  const int row0 = blockIdx.y * 256 + wm + (lane >> 4) * 4;
  const int col0 = blockIdx.x * 128 + wn + fr;
#pragma unroll
  for (int mi = 0; mi < 4; mi++) {
#pragma unroll
    for (int i = 0; i < 4; i++) {
      const size_t roff = cbase + (size_t)(row0 + mi * 16 + i) * ldc + col0;
#pragma unroll
      for (int ni = 0; ni < 4; ni++) {
        float v = acc[mi][ni][i];
        if constexpr (BF16OUT)
          ((u16*)Cout)[roff + ni * 16] = f2bf(v);
        else
          ((float*)Cout)[roff + ni * 16] = v;
      }
    }
  }
}

// One block per row of 2048 bf16 logits -> bf16 probabilities, IN PLACE.
__global__ __launch_bounds__(256) void softmax_rows_bf16(u16* __restrict__ SP) {
  const size_t row = blockIdx.x;
  us8* p = (us8*)(SP + row * 2048);
  const int t = threadIdx.x;
  us8 raw = p[t];
  float v[8];
#pragma unroll
  for (int i = 0; i < 8; i++) v[i] = bf2f(raw[i]);

  float m = v[0];
#pragma unroll
  for (int i = 1; i < 8; i++) m = fmaxf(m, v[i]);
#pragma unroll
  for (int o = 32; o; o >>= 1) m = fmaxf(m, __shfl_xor(m, o, 64));
  __shared__ float redm[4];
  if ((t & 63) == 0) redm[t >> 6] = m;
  __syncthreads();
  m = fmaxf(fmaxf(redm[0], redm[1]), fmaxf(redm[2], redm[3]));

  float sum = 0.f;
#pragma unroll
  for (int i = 0; i < 8; i++) { v[i] = __expf(v[i] - m); sum += v[i]; }
#pragma unroll
  for (int o = 32; o; o >>= 1) sum += __shfl_xor(sum, o, 64);
  __shared__ float reds[4];
  if ((t & 63) == 0) reds[t >> 6] = sum;
  __syncthreads();
  sum = reds[0] + reds[1] + reds[2] + reds[3];
  const float r = 1.0f / sum;

  us8 o;
#pragma unroll
  for (int i = 0; i < 8; i++) o[i] = f2bf(v[i] * r);
  p[t] = o;
}

extern "C" void kernel_launch(void* const* d_in, const int* in_sizes, int n_in,
                              void* d_out, int out_size, void* d_ws, size_t ws_size,
                              hipStream_t stream) {
  const float* x   = (const float*)d_in[0];  // [8,2048,1024]
  const float* ctx = (const float*)d_in[1];  // [8,2048,1024]
  const float* Wq  = (const float*)d_in[2];  // [1024,1024]
  const float* Wk  = (const float*)d_in[3];
  const float* Wv  = (const float*)d_in[4];
  float* out = (float*)d_out;                // [8,2048,1024] f32

  const size_t NT = 8ull * 2048 * 1024;      // 16,777,216 elements

  // d_ws layout (u16 elements; total 107 MB):
  //   xbf [0,NT)  cbf [NT,2NT)  -> both dead after projections -> S overlays
  //   Vt  [2NT,3NT)   Wqb/Wkb/Wvb [3NT, 3NT+3M)
  u16* wsu  = (u16*)d_ws;
  u16* xbf  = wsu;
  u16* cbf  = wsu + NT;
  u16* Sbuf = wsu;                 // overlays xbf+cbf (67 MB, 8 batches)
  u16* Vt   = wsu + 2 * NT;
  u16* Wqb  = wsu + 3 * NT;        // Wqb,Wkb,Wvb contiguous (1M elems each)
  // d_out doubles as bf16 Q [0,NT) and K [NT,2NT) until PV overwrites it.
  u16* Qbf = (u16*)d_out;

  dim3 blk(256), gblk(512);

  // 1) converts (2 dispatches)
  cvt_xc<<<dim3(32768), blk, 0, stream>>>((const float4*)x, (const float4*)ctx,
                                          (us4*)xbf, (us4*)cbf);
  cvt_w<<<dim3(3072), blk, 0, stream>>>((const float4*)Wq, (const float4*)Wk,
                                        (const float4*)Wv, (us4*)Wqb);

  // 2) [Q|K] projection, batched z=0/1: M=16384 N=1024 K=1024.
  gemm_nt<true><<<dim3(8, 64, 2), gblk, 0, stream>>>(
      xbf, Wqb, Qbf, 1024, 1024, 1024, 1024,
      (long)NT, 1024L * 1024, (long)NT);
  // Vt[b,e,t] = Wv @ ctx_b^T : per batch M=1024 N=2048 K=1024
  gemm_nt<true><<<dim3(16, 4, 8), gblk, 0, stream>>>(
      Wqb + 2 * 1024 * 1024, cbf, Vt, 1024, 1024, 2048, 1024,
      0L, 2048L * 1024, 1024L * 2048);

  // 3) S[b,s,t] = Q_b @ K_b^T : 8 batches, M=2048 N=2048 K=1024, bf16 out
  gemm_nt<true><<<dim3(16, 8, 8), gblk, 0, stream>>>(
      Qbf, Qbf + NT, Sbuf, 1024, 1024, 2048, 1024,
      2048L * 1024, 2048L * 1024, 2048L * 2048);

  // 4) softmax in place: 16384 rows of 2048
  softmax_rows_bf16<<<dim3(16384), blk, 0, stream>>>(Sbuf);

  // 5) out[b,s,e] = P_b @ Vt_b^T : M=2048 N=1024 K=2048, f32 out (overwrites
  //    dead Q/K in d_out; stream-ordered after step 3/4)
  gemm_nt<false><<<dim3(8, 8, 8), gblk, 0, stream>>>(
      Sbuf, Vt, out, 2048, 2048, 1024, 2048,
      2048L * 2048, 1024L * 2048, 2048L * 1024);
}

// Round 7
// 478.755 us; speedup vs baseline: 1.2782x; 1.0737x over previous
//
#include <hip/hip_runtime.h>

// CrossAttention (B=8, Sq=Skv=2048, D=1024), fp32 in/out, bf16 MFMA compute.
//
// Full-batch pipeline (ws usage 107 MB; Q AND K parked in d_out as bf16):
//   1) cvt fp32->bf16: {x,ctx} -> xbf,cbf ; {Wq*(1/32),Wk,Wv} -> Wqb,Wkb,Wvb
//   2) [Q|K] = [x|ctx] @ [Wq|Wk]^T  (one batched NT GEMM) -> d_out bf16
//      Vt[b,e,t] = Wv@ctx^T (V transposed so PV is NT)    -> ws
//   3) S[b,s,t] = Q@K^T (8 batches) -> bf16 S overlays dead xbf+cbf
//   4) softmax rows in place (16384 rows)
//   5) out = P@Vt^T (f32) -> d_out, overwriting dead Q/K (stream-ordered)
//
// GEMM: 256x128 block tile, BK=32, 512 thr = 8 waves (each 64x64 via 4x4
// mfma_f32_16x16x32_bf16), global_load_lds width=16 staging, 2-barrier K-loop.
// 1D grid + XCD-aware swizzle: HW assigns XCD = blockIdx % 8 (round-robin);
// remap gid=(p%8)*slab+(p/8) gives each XCD a contiguous x-innermost slab ->
// one batch per XCD for the attention GEMMs, A-panel sharers co-located.
// NOTE: grid size MUST equal nx*ny*nz exactly (decode is a bijection).

typedef unsigned short u16;
typedef __bf16 bf16x8 __attribute__((ext_vector_type(8)));
typedef float f32x4 __attribute__((ext_vector_type(4)));
typedef u16 us8 __attribute__((ext_vector_type(8)));

__device__ __forceinline__ u16 f2bf(float f) {
  unsigned int u = __float_as_uint(f);
  u += 0x7fffu + ((u >> 16) & 1u);   // round-to-nearest-even
  return (u16)(u >> 16);
}
__device__ __forceinline__ float bf2f(u16 h) {
  return __uint_as_float((unsigned int)h << 16);
}

struct __attribute__((aligned(8))) us4 { u16 x, y, z, w; };

// x (4194304 float4) -> xbf ; ctx -> cbf. One dispatch.
__global__ __launch_bounds__(256) void cvt_xc(const float4* __restrict__ x,
                                              const float4* __restrict__ c,
                                              us4* __restrict__ dx,
                                              us4* __restrict__ dc) {
  int i = blockIdx.x * 256 + threadIdx.x;
  const float4* s = (i < 4194304) ? x : (c - 4194304);
  us4* d = (i < 4194304) ? dx : (dc - 4194304);
  float4 v = s[i];
  us4 o{f2bf(v.x), f2bf(v.y), f2bf(v.z), f2bf(v.w)};
  d[i] = o;
}

// Wq*(1/32), Wk, Wv -> bf16 (each 262144 float4). One dispatch, 3072 blocks.
__global__ __launch_bounds__(256) void cvt_w(const float4* __restrict__ wq,
                                             const float4* __restrict__ wk,
                                             const float4* __restrict__ wv,
                                             us4* __restrict__ d) {
  int i = blockIdx.x * 256 + threadIdx.x;
  const float4* s; float sc;
  if (i < 262144)      { s = wq;           sc = 0.03125f; }
  else if (i < 524288) { s = wk - 262144;  sc = 1.0f; }
  else                 { s = wv - 524288;  sc = 1.0f; }
  float4 v = s[i];
  us4 o{f2bf(v.x * sc), f2bf(v.y * sc), f2bf(v.z * sc), f2bf(v.w * sc)};
  d[i] = o;
}

// C-style casts: static_cast cannot both drop const and change address space.
__device__ __forceinline__ void gload16(const u16* g, u16* l) {
  __builtin_amdgcn_global_load_lds(
      (const __attribute__((address_space(1))) unsigned int*)g,
      (__attribute__((address_space(3))) unsigned int*)l,
      16, 0, 0);
}

// NT GEMM: C[m,n] = sum_k A[m,k]*B[n,k].  A:[M][lda] B:[N][ldb] bf16
// row-major. 1D grid of EXACTLY nx*ny*nz blocks (divisible by 8), 512 thr.
template <bool BF16OUT>
__global__ __launch_bounds__(512) void gemm_nt(
    const u16* __restrict__ A, const u16* __restrict__ B, void* __restrict__ Cout,
    int lda, int ldb, int ldc, int K,
    long batchA, long batchB, long batchC, int nx, int ny) {
  __shared__ u16 sA[256 * 32];   // 16 KB
  __shared__ u16 sB[128 * 32];   //  8 KB

  // XCD-aware swizzle: XCD = p%8 (HW round-robin); give each XCD a
  // contiguous slab of the (z,y,x) space, x innermost.
  const int p    = blockIdx.x;
  const int slab = gridDim.x >> 3;
  const int gid  = (p & 7) * slab + (p >> 3);
  const int bx   = gid % nx;
  const int t2   = gid / nx;
  const int by   = t2 % ny;
  const int z    = t2 / ny;

  const int tid  = threadIdx.x;          // 0..511
  const int lane = tid & 63;
  const int wv   = tid >> 6;             // wave 0..7

  const u16* Ab = A + (size_t)z * batchA + (size_t)by * 256 * lda;
  const u16* Bb = B + (size_t)z * batchB + (size_t)bx * 128 * ldb;

  // staging: 512 threads, 4 lanes per row (64-B contiguous runs).
  const int srow = tid >> 2;             // 0..127
  const int scol = (tid & 3) * 8;        // colgroup (8 bf16 = 16 B)

  const u16* gA0 = Ab + (size_t)srow * lda + scol;          // rows 0..127
  const u16* gA1 = Ab + (size_t)(128 + srow) * lda + scol;  // rows 128..255
  const u16* gB  = Bb + (size_t)srow * ldb + scol;          // rows 0..127

  // fragment addressing (per wave: 64x64 tile, 4x4 frags of 16x16x32)
  const int fr = lane & 15;              // m (A) / n (B) within 16
  const int fq = (lane >> 4) * 8;        // k offset within 32
  const int wm = (wv & 3) * 64;          // wave m-offset (0..192)
  const int wn = (wv >> 2) * 64;         // wave n-offset (0 or 64)

  f32x4 acc[4][4];
#pragma unroll
  for (int i = 0; i < 4; i++)
#pragma unroll
    for (int j = 0; j < 4; j++) acc[i][j] = (f32x4)0.f;

  for (int k0 = 0; k0 < K; k0 += 32) {
    // LDS dest = wave-uniform base + lane*16 (tid*16 decomposes as such)
    gload16(gA0 + k0, &sA[tid * 8]);
    gload16(gA1 + k0, &sA[4096 + tid * 8]);
    gload16(gB  + k0, &sB[tid * 8]);
    __syncthreads();   // compiler drains vmcnt(0) before s_barrier

    bf16x8 av[4], bv[4];
#pragma unroll
    for (int i = 0; i < 4; i++)
      av[i] = *(const bf16x8*)&sA[(wm + i * 16 + fr) * 32 + fq];
#pragma unroll
    for (int i = 0; i < 4; i++)
      bv[i] = *(const bf16x8*)&sB[(wn + i * 16 + fr) * 32 + fq];
#pragma unroll
    for (int mi = 0; mi < 4; mi++)
#pragma unroll
      for (int ni = 0; ni < 4; ni++)
        acc[mi][ni] = __builtin_amdgcn_mfma_f32_16x16x32_bf16(
            av[mi], bv[ni], acc[mi][ni], 0, 0, 0);
    __syncthreads();   // protect LDS before next stage overwrites
  }

  // epilogue: C/D layout col=lane&15, row=(lane>>4)*4+reg  [m89/m91 verified]
  const size_t cbase = (size_t)z * batchC;
  const int row0 = by * 256 + wm + (lane >> 4) * 4;
  const int col0 = bx * 128 + wn + fr;
#pragma unroll
  for (int mi = 0; mi < 4; mi++) {
#pragma unroll
    for (int i = 0; i < 4; i++) {
      const size_t roff = cbase + (size_t)(row0 + mi * 16 + i) * ldc + col0;
#pragma unroll
      for (int ni = 0; ni < 4; ni++) {
        float v = acc[mi][ni][i];
        if constexpr (BF16OUT)
          ((u16*)Cout)[roff + ni * 16] = f2bf(v);
        else
          ((float*)Cout)[roff + ni * 16] = v;
      }
    }
  }
}

// One block per row of 2048 bf16 logits -> bf16 probabilities, IN PLACE.
__global__ __launch_bounds__(256) void softmax_rows_bf16(u16* __restrict__ SP) {
  const size_t row = blockIdx.x;
  us8* p = (us8*)(SP + row * 2048);
  const int t = threadIdx.x;
  us8 raw = p[t];
  float v[8];
#pragma unroll
  for (int i = 0; i < 8; i++) v[i] = bf2f(raw[i]);

  float m = v[0];
#pragma unroll
  for (int i = 1; i < 8; i++) m = fmaxf(m, v[i]);
#pragma unroll
  for (int o = 32; o; o >>= 1) m = fmaxf(m, __shfl_xor(m, o, 64));
  __shared__ float redm[4];
  if ((t & 63) == 0) redm[t >> 6] = m;
  __syncthreads();
  m = fmaxf(fmaxf(redm[0], redm[1]), fmaxf(redm[2], redm[3]));

  float sum = 0.f;
#pragma unroll
  for (int i = 0; i < 8; i++) { v[i] = __expf(v[i] - m); sum += v[i]; }
#pragma unroll
  for (int o = 32; o; o >>= 1) sum += __shfl_xor(sum, o, 64);
  __shared__ float reds[4];
  if ((t & 63) == 0) reds[t >> 6] = sum;
  __syncthreads();
  sum = reds[0] + reds[1] + reds[2] + reds[3];
  const float r = 1.0f / sum;

  us8 o;
#pragma unroll
  for (int i = 0; i < 8; i++) o[i] = f2bf(v[i] * r);
  p[t] = o;
}

extern "C" void kernel_launch(void* const* d_in, const int* in_sizes, int n_in,
                              void* d_out, int out_size, void* d_ws, size_t ws_size,
                              hipStream_t stream) {
  const float* x   = (const float*)d_in[0];  // [8,2048,1024]
  const float* ctx = (const float*)d_in[1];  // [8,2048,1024]
  const float* Wq  = (const float*)d_in[2];  // [1024,1024]
  const float* Wk  = (const float*)d_in[3];
  const float* Wv  = (const float*)d_in[4];
  float* out = (float*)d_out;                // [8,2048,1024] f32

  const size_t NT = 8ull * 2048 * 1024;      // 16,777,216 elements

  // d_ws layout (u16 elements; total 107 MB):
  //   xbf [0,NT)  cbf [NT,2NT)  -> both dead after projections -> S overlays
  //   Vt  [2NT,3NT)   Wqb/Wkb/Wvb [3NT, 3NT+3M)
  u16* wsu  = (u16*)d_ws;
  u16* xbf  = wsu;
  u16* cbf  = wsu + NT;
  u16* Sbuf = wsu;                 // overlays xbf+cbf (67 MB, 8 batches)
  u16* Vt   = wsu + 2 * NT;
  u16* Wqb  = wsu + 3 * NT;        // Wqb,Wkb,Wvb contiguous (1M elems each)
  // d_out doubles as bf16 Q [0,NT) and K [NT,2NT) until PV overwrites it.
  u16* Qbf = (u16*)d_out;

  dim3 blk(256), gblk(512);

  // 1) converts (2 dispatches)
  cvt_xc<<<dim3(32768), blk, 0, stream>>>((const float4*)x, (const float4*)ctx,
                                          (us4*)xbf, (us4*)cbf);
  cvt_w<<<dim3(3072), blk, 0, stream>>>((const float4*)Wq, (const float4*)Wk,
                                        (const float4*)Wv, (us4*)Wqb);

  // 2) [Q|K] projection: M=16384 N=1024 K=1024, z=0/1. nx*ny*nz=8*64*2=1024.
  gemm_nt<true><<<dim3(1024), gblk, 0, stream>>>(
      xbf, Wqb, Qbf, 1024, 1024, 1024, 1024,
      (long)NT, 1024L * 1024, (long)NT, 8, 64);
  // Vt[b,e,t] = Wv @ ctx_b^T : M=1024 N=2048 K=1024. nx*ny*nz=16*4*8=512.
  gemm_nt<true><<<dim3(512), gblk, 0, stream>>>(
      Wqb + 2 * 1024 * 1024, cbf, Vt, 1024, 1024, 2048, 1024,
      0L, 2048L * 1024, 1024L * 2048, 16, 4);

  // 3) S = Q@K^T : 8 batches, M=2048 N=2048 K=1024, bf16 out.
  //    nx*ny*nz = 16*8*8 = 1024 blocks; slab=128 = one batch per XCD.
  gemm_nt<true><<<dim3(1024), gblk, 0, stream>>>(
      Qbf, Qbf + NT, Sbuf, 1024, 1024, 2048, 1024,
      2048L * 1024, 2048L * 1024, 2048L * 2048, 16, 8);

  // 4) softmax in place: 16384 rows of 2048
  softmax_rows_bf16<<<dim3(16384), blk, 0, stream>>>(Sbuf);

  // 5) out = P@Vt^T : M=2048 N=1024 K=2048, f32 out. nx*ny*nz=8*8*8=512 ->
  //    one batch per XCD. Overwrites dead Q/K in d_out (stream-ordered).
  gemm_nt<false><<<dim3(512), gblk, 0, stream>>>(
      Sbuf, Vt, out, 2048, 2048, 1024, 2048,
      2048L * 2048, 1024L * 2048, 2048L * 1024, 8, 8);
}